// Round 19
// baseline (414.303 us; speedup 1.0000x reference)
//
#include <hip/hip_runtime.h>

#define B_DIM 8
#define S_LEN 4096
#define D_DIM 512
#define H_DIM 512

#define DECAY_F 0.90483743f   // exp(-0.1)
#define ALPHA_F 0.01f
#define EPS_F   1e-6f

#define KT 16
#define NCHUNK (S_LEN / 32)   // 128
#define NSCAN_BLOCKS 64

// ================= GEMM tile body (R7/R11 exact, proven) =========================
__device__ __forceinline__ void gemm_tile(const float* __restrict__ x,
                                          const float* __restrict__ W,
                                          const float* __restrict__ bias,
                                          float* __restrict__ out,
                                          float (*As)[132], float (*Bs)[132],
                                          int bm, int bn) {
    const int tid = threadIdx.x;
    const int waveId = tid >> 6;
    const int waveR = waveId & 1;
    const int waveC = waveId >> 1;
    const int lane = tid & 63;
    const int tr = lane >> 3;
    const int tc = lane & 7;
    const int rbase = waveR * 64 + tr * 8;
    const int c0 = waveC * 64 + tc * 4;
    const int c1 = c0 + 32;

    const int lrow = tid >> 2;
    const int lk4  = (tid & 3) * 4;

    const float* xa = &x[(size_t)(bm + lrow) * D_DIM + lk4];
    const float* xb = &x[(size_t)(bm + lrow + 64) * D_DIM + lk4];
    const float* wa = &W[(size_t)(bn + lrow) * D_DIM + lk4];
    const float* wb = &W[(size_t)(bn + lrow + 64) * D_DIM + lk4];

    float acc[8][8];
#pragma unroll
    for (int i = 0; i < 8; ++i)
#pragma unroll
        for (int j = 0; j < 8; ++j) acc[i][j] = 0.f;

    float4 a0 = *reinterpret_cast<const float4*>(xa);
    float4 a1 = *reinterpret_cast<const float4*>(xb);
    float4 b0 = *reinterpret_cast<const float4*>(wa);
    float4 b1 = *reinterpret_cast<const float4*>(wb);

    for (int kk = 0; kk < D_DIM; kk += KT) {
        __syncthreads();
        As[lk4 + 0][lrow]      = a0.x;
        As[lk4 + 1][lrow]      = a0.y;
        As[lk4 + 2][lrow]      = a0.z;
        As[lk4 + 3][lrow]      = a0.w;
        As[lk4 + 0][lrow + 64] = a1.x;
        As[lk4 + 1][lrow + 64] = a1.y;
        As[lk4 + 2][lrow + 64] = a1.z;
        As[lk4 + 3][lrow + 64] = a1.w;
        Bs[lk4 + 0][lrow]      = b0.x;
        Bs[lk4 + 1][lrow]      = b0.y;
        Bs[lk4 + 2][lrow]      = b0.z;
        Bs[lk4 + 3][lrow]      = b0.w;
        Bs[lk4 + 0][lrow + 64] = b1.x;
        Bs[lk4 + 1][lrow + 64] = b1.y;
        Bs[lk4 + 2][lrow + 64] = b1.z;
        Bs[lk4 + 3][lrow + 64] = b1.w;
        __syncthreads();

        if (kk + KT < D_DIM) {
            a0 = *reinterpret_cast<const float4*>(xa + kk + KT);
            a1 = *reinterpret_cast<const float4*>(xb + kk + KT);
            b0 = *reinterpret_cast<const float4*>(wa + kk + KT);
            b1 = *reinterpret_cast<const float4*>(wb + kk + KT);
        }

#pragma unroll
        for (int k = 0; k < KT; ++k) {
            const float4 av0 = *reinterpret_cast<const float4*>(&As[k][rbase]);
            const float4 av1 = *reinterpret_cast<const float4*>(&As[k][rbase + 4]);
            const float4 bv0 = *reinterpret_cast<const float4*>(&Bs[k][c0]);
            const float4 bv1 = *reinterpret_cast<const float4*>(&Bs[k][c1]);
            const float am[8]  = {av0.x, av0.y, av0.z, av0.w, av1.x, av1.y, av1.z, av1.w};
            const float bn_[8] = {bv0.x, bv0.y, bv0.z, bv0.w, bv1.x, bv1.y, bv1.z, bv1.w};
#pragma unroll
            for (int i = 0; i < 8; ++i)
#pragma unroll
                for (int j = 0; j < 8; ++j) acc[i][j] += am[i] * bn_[j];
        }
    }

    const float4 bias0 = *reinterpret_cast<const float4*>(&bias[bn + c0]);
    const float4 bias1 = *reinterpret_cast<const float4*>(&bias[bn + c1]);
    const float bb[8] = {bias0.x, bias0.y, bias0.z, bias0.w, bias1.x, bias1.y, bias1.z, bias1.w};

#pragma unroll
    for (int i = 0; i < 8; ++i) {
        const size_t row = (size_t)(bm + rbase + i);
        float4 o0, o1;
        o0.x = acc[i][0] + bb[0]; o0.y = acc[i][1] + bb[1];
        o0.z = acc[i][2] + bb[2]; o0.w = acc[i][3] + bb[3];
        o1.x = acc[i][4] + bb[4]; o1.y = acc[i][5] + bb[5];
        o1.z = acc[i][6] + bb[6]; o1.w = acc[i][7] + bb[7];
        *reinterpret_cast<float4*>(&out[row * H_DIM + bn + c0]) = o0;
        *reinterpret_cast<float4*>(&out[row * H_DIM + bn + c1]) = o1;
    }
}

// ================= Scan (R11 exact: 64 blocks, 1 chain/lane, proven) =============
__device__ __forceinline__ void stage_chunk(const float* __restrict__ gio, float* dstbase,
                                            int c, int lane) {
    const float* src = gio + (size_t)(c * 32 + (lane >> 4)) * H_DIM + ((lane & 15) << 2);
#pragma unroll
    for (int i = 0; i < 8; ++i) {
        __builtin_amdgcn_global_load_lds(
            (const __attribute__((address_space(1))) void*)(src + (size_t)i * 4 * H_DIM),
            (__attribute__((address_space(3))) void*)(dstbase + i * 256),
            16, 0, 0);
    }
}

__device__ __forceinline__ void scan_wave(float* __restrict__ gio, float* sbuf,
                                          const int* flagrow, int lane,
                                          float* __restrict__ vout,
                                          float* __restrict__ thout, int chain) {
    float v = 0.f;
    float theta = 1.f;
    float tden = theta + EPS_F;
    float rs = __builtin_amdgcn_rcpf(tden);
    float es = fmaf(-tden, rs, 1.0f);
    float r1 = fmaf(es, rs, rs);
    float es2 = fmaf(-tden, r1, 1.0f);
    float r0 = fmaf(es2, r1, r1);
    float cl = 32.f * theta;
    const float kSixteen = 16.0f;

    if (flagrow) {
        while (__hip_atomic_load(&flagrow[0], __ATOMIC_ACQUIRE, __HIP_MEMORY_SCOPE_AGENT) < 4)
            __builtin_amdgcn_s_sleep(1);
    }
    stage_chunk(gio, sbuf, 0, lane);
    asm volatile("s_waitcnt vmcnt(0)" ::: "memory");

    for (int c = 0; c < NCHUNK; ++c) {
        if (c + 1 < NCHUNK) {
            if (((c + 1) & 3) == 0 && flagrow) {
                const int stn = (c + 1) >> 2;
                while (__hip_atomic_load(&flagrow[stn], __ATOMIC_ACQUIRE,
                                         __HIP_MEMORY_SCOPE_AGENT) < 4)
                    __builtin_amdgcn_s_sleep(1);
                asm volatile("s_waitcnt vmcnt(0)" ::: "memory");
                stage_chunk(gio, sbuf + ((c + 1) & 1) * 2048, c + 1, lane);
            } else {
                stage_chunk(gio, sbuf + ((c + 1) & 1) * 2048, c + 1, lane);
                // outstanding: stage(c)=8, stores(c-1)=32, stage(c+1)=8 -> retire oldest 8
                asm volatile("s_waitcnt vmcnt(40)" ::: "memory");
            }
        } else {
            asm volatile("s_waitcnt vmcnt(32)" ::: "memory");
        }
        __builtin_amdgcn_sched_barrier(0);

        const float* sb = sbuf + (c & 1) * 2048 + lane;
        float rr[32];
#pragma unroll
        for (int i = 0; i < 32; ++i) rr[i] = sb[i * 64];
        __builtin_amdgcn_sched_barrier(0);

        float* gout = gio + (size_t)c * 32 * H_DIM + lane;

#pragma unroll
        for (int u = 0; u < 32; ++u) {
            float vv = v * DECAY_F + rr[u];
            asm("v_med3_f32 %0, %0, -%1, %1" : "+v"(vv) : "v"(cl));
            v = vv;

            const float q0 = v * r0;
            const float e1 = fmaf(-tden, q0, v);
            const float nv = fmaf(e1, r0, q0);

            float spike = floorf(nv);
            asm("v_med3_f32 %0, %0, 0, %1" : "+v"(spike) : "v"(kSixteen));

            v = v - spike * theta;
            theta = theta + ALPHA_F * spike - ALPHA_F * (theta - 1.0f);

            tden = theta + EPS_F;
            const float rrcp = __builtin_amdgcn_rcpf(tden);
            const float ee = fmaf(-tden, rrcp, 1.0f);
            const float ra = fmaf(ee, rrcp, rrcp);
            const float ee2 = fmaf(-tden, ra, 1.0f);
            r0 = fmaf(ee2, ra, ra);
            cl = 32.f * theta;

            gout[(size_t)u * H_DIM] = spike;
        }
        __builtin_amdgcn_sched_barrier(0);
    }

    vout[chain]  = v;
    thout[chain] = theta;
}

// ================= fused kernel: R11 + LDS-forced 2 blocks/CU ====================
// ONLY change vs R11 (334us proven): static LDS padded 16896 -> 55296 bytes so at
// most 2 blocks fit per CU (2x55296 <= 160KB < 3x55296). Effect: of the 1088
// blocks only ~450-512 are resident; the rest sit in the HW dispatch queue and
// issue to whichever CU frees a slot -> perfect load balance (R18's static
// 2-tiles-per-block skewed 64 CUs to 1.5x work) AND continuous, s-ordered tile
// completion (R11's full co-residency finished every tile simultaneously ->
// zero overlap). Scan (resident from t=0) starts draining at ~T/2 and trails
// production by ~1 s-tile. 2 blocks/CU keeps barrier-bubble cover (R12's
// 1-block/CU did not).
// blocks 0..63: scan, ONE active wave (threads 64..255 exit), 16KB dbuf, setprio.
// blocks 64..1087: GEMM 128x128 tiles, s-tile-major (st = g>>5).
// Sync: flags[bb*32+st] count to 4; __syncthreads drains stores, tid-0 RELEASE
// fetch_add; scan ACQUIRE-polls ==4. Protocol proven R10-R12.
__global__ __launch_bounds__(256) void fused_kernel(const float* __restrict__ x,
                                                    const float* __restrict__ W,
                                                    const float* __restrict__ bias,
                                                    float* __restrict__ out,
                                                    float* __restrict__ vout,
                                                    float* __restrict__ thout,
                                                    int* __restrict__ flags) {
    __shared__ __align__(16) char smem_raw[55296];   // 54KB -> exactly 2 blocks/CU
    const int bid = blockIdx.x;

    if (bid >= NSCAN_BLOCKS) {
        float (*As)[132] = reinterpret_cast<float (*)[132]>(smem_raw);
        float (*Bs)[132] = reinterpret_cast<float (*)[132]>(smem_raw + sizeof(float) * KT * 132);

        const int g  = bid - NSCAN_BLOCKS;   // 0..1023
        const int st = g >> 5;               // s-tile 0..31 (outer)
        const int bb = (g >> 2) & 7;         // batch
        const int nt = g & 3;                // n-tile
        const int bm = bb * S_LEN + st * 128;
        const int bn = nt * 128;

        gemm_tile(x, W, bias, out, As, Bs, bm, bn);

        __syncthreads();   // all waves' stores retired before the release add
        if (threadIdx.x == 0) {
            __hip_atomic_fetch_add(&flags[bb * 32 + st], 1,
                                   __ATOMIC_RELEASE, __HIP_MEMORY_SCOPE_AGENT);
        }
        return;
    }

    // scan role: one active wave per block
    if (threadIdx.x >= 64) return;
    __builtin_amdgcn_s_setprio(1);

    const int lane = threadIdx.x;
    const int b  = bid >> 3;             // 0..7
    const int h0 = (bid & 7) << 6;       // 0,64,...,448

    float* sbuf = reinterpret_cast<float*>(smem_raw);
    float* gio = out + (size_t)b * S_LEN * H_DIM + h0;
    const int chain = b * H_DIM + h0 + lane;

    scan_wave(gio, sbuf, flags + b * 32, lane, vout, thout, chain);
}

// ================= fallback serial kernels (ws too small) ========================

__global__ __launch_bounds__(256) void gemm_kernel(const float* __restrict__ x,
                                                   const float* __restrict__ W,
                                                   const float* __restrict__ bias,
                                                   float* __restrict__ out) {
    __shared__ float As[KT][132];
    __shared__ float Bs[KT][132];
    const int bm = blockIdx.y * 128;
    const int bn = blockIdx.x * 128;
    gemm_tile(x, W, bias, out, As, Bs, bm, bn);
}

__global__ __launch_bounds__(64, 1) void scan_serial_kernel(float* __restrict__ io,
                                                            float* __restrict__ vout,
                                                            float* __restrict__ thout) {
    __shared__ __align__(16) float sbuf[4096];
    const int bid = blockIdx.x;
    const int lane = threadIdx.x;
    const int b  = bid >> 3;
    const int h0 = (bid & 7) << 6;
    float* gio = io + (size_t)b * S_LEN * H_DIM + h0;
    const int chain = b * H_DIM + h0 + lane;
    scan_wave(gio, sbuf, nullptr, lane, vout, thout, chain);
}

extern "C" void kernel_launch(void* const* d_in, const int* in_sizes, int n_in,
                              void* d_out, int out_size, void* d_ws, size_t ws_size,
                              hipStream_t stream) {
    const float* x    = (const float*)d_in[0];
    const float* W    = (const float*)d_in[1];
    const float* bias = (const float*)d_in[2];

    float* out   = (float*)d_out;
    float* vout  = out + (size_t)B_DIM * S_LEN * H_DIM;
    float* thout = vout + B_DIM * H_DIM;

    if (ws_size >= 1024) {
        int* flags = (int*)d_ws;
        hipMemsetAsync(flags, 0, 1024, stream);
        fused_kernel<<<NSCAN_BLOCKS + 1024, 256, 0, stream>>>(x, W, bias, out,
                                                              vout, thout, flags);
    } else {
        dim3 grid(H_DIM / 128, (B_DIM * S_LEN) / 128);
        gemm_kernel<<<grid, 256, 0, stream>>>(x, W, bias, out);
        scan_serial_kernel<<<NSCAN_BLOCKS, 64, 0, stream>>>(out, vout, thout);
    }
}

// Round 20
// 325.229 us; speedup vs baseline: 1.2739x; 1.2739x over previous
//
#include <hip/hip_runtime.h>

#define B_DIM 8
#define S_LEN 4096
#define D_DIM 512
#define H_DIM 512

#define DECAY_F 0.90483743f   // exp(-0.1)
#define ALPHA_F 0.01f
#define EPS_F   1e-6f

#define KT 32
#define NCHUNK (S_LEN / 32)   // 128
#define NSCAN_BLOCKS 64

// ================= GEMM tile body: R7/R11 mapping, KT=32 (half the barriers) =====
// Same 8x8 wave grid (tr=lane>>3, tc=lane&7, cols {c0,c0+32} -> conflict-free
// B-reads, 2-way A-reads, dense 128B stores). KT 16->32: 32 barriers/tile instead
// of 64 (R11's GEMM lost ~40% of its time to barrier drain; halves that), LDS
// 33.8KB -> still 4 blocks/CU. Inner k 0..31 over the same ascending global-k
// sequence -> per-element accumulation order identical since R2 -> bit-identical h.
__device__ __forceinline__ void gemm_tile(const float* __restrict__ x,
                                          const float* __restrict__ W,
                                          const float* __restrict__ bias,
                                          float* __restrict__ out,
                                          float (*As)[132], float (*Bs)[132],
                                          int bm, int bn) {
    const int tid = threadIdx.x;
    const int waveId = tid >> 6;
    const int waveR = waveId & 1;
    const int waveC = waveId >> 1;
    const int lane = tid & 63;
    const int tr = lane >> 3;
    const int tc = lane & 7;
    const int rbase = waveR * 64 + tr * 8;
    const int c0 = waveC * 64 + tc * 4;
    const int c1 = c0 + 32;

    const int lrow = tid >> 2;          // 0..63
    const int lk4  = (tid & 3) * 4;     // 0,4,8,12

    const float* xa = &x[(size_t)(bm + lrow) * D_DIM + lk4];
    const float* xb = &x[(size_t)(bm + lrow + 64) * D_DIM + lk4];
    const float* wa = &W[(size_t)(bn + lrow) * D_DIM + lk4];
    const float* wb = &W[(size_t)(bn + lrow + 64) * D_DIM + lk4];

    float acc[8][8];
#pragma unroll
    for (int i = 0; i < 8; ++i)
#pragma unroll
        for (int j = 0; j < 8; ++j) acc[i][j] = 0.f;

    // prologue: stage k-tile 0 (two 16-wide halves per row) into registers
    float4 a0l = *reinterpret_cast<const float4*>(xa);
    float4 a0h = *reinterpret_cast<const float4*>(xa + 16);
    float4 a1l = *reinterpret_cast<const float4*>(xb);
    float4 a1h = *reinterpret_cast<const float4*>(xb + 16);
    float4 b0l = *reinterpret_cast<const float4*>(wa);
    float4 b0h = *reinterpret_cast<const float4*>(wa + 16);
    float4 b1l = *reinterpret_cast<const float4*>(wb);
    float4 b1h = *reinterpret_cast<const float4*>(wb + 16);

    for (int kk = 0; kk < D_DIM; kk += KT) {
        __syncthreads();
        As[lk4 + 0][lrow]       = a0l.x;
        As[lk4 + 1][lrow]       = a0l.y;
        As[lk4 + 2][lrow]       = a0l.z;
        As[lk4 + 3][lrow]       = a0l.w;
        As[lk4 + 16][lrow]      = a0h.x;
        As[lk4 + 17][lrow]      = a0h.y;
        As[lk4 + 18][lrow]      = a0h.z;
        As[lk4 + 19][lrow]      = a0h.w;
        As[lk4 + 0][lrow + 64]  = a1l.x;
        As[lk4 + 1][lrow + 64]  = a1l.y;
        As[lk4 + 2][lrow + 64]  = a1l.z;
        As[lk4 + 3][lrow + 64]  = a1l.w;
        As[lk4 + 16][lrow + 64] = a1h.x;
        As[lk4 + 17][lrow + 64] = a1h.y;
        As[lk4 + 18][lrow + 64] = a1h.z;
        As[lk4 + 19][lrow + 64] = a1h.w;
        Bs[lk4 + 0][lrow]       = b0l.x;
        Bs[lk4 + 1][lrow]       = b0l.y;
        Bs[lk4 + 2][lrow]       = b0l.z;
        Bs[lk4 + 3][lrow]       = b0l.w;
        Bs[lk4 + 16][lrow]      = b0h.x;
        Bs[lk4 + 17][lrow]      = b0h.y;
        Bs[lk4 + 18][lrow]      = b0h.z;
        Bs[lk4 + 19][lrow]      = b0h.w;
        Bs[lk4 + 0][lrow + 64]  = b1l.x;
        Bs[lk4 + 1][lrow + 64]  = b1l.y;
        Bs[lk4 + 2][lrow + 64]  = b1l.z;
        Bs[lk4 + 3][lrow + 64]  = b1l.w;
        Bs[lk4 + 16][lrow + 64] = b1h.x;
        Bs[lk4 + 17][lrow + 64] = b1h.y;
        Bs[lk4 + 18][lrow + 64] = b1h.z;
        Bs[lk4 + 19][lrow + 64] = b1h.w;
        __syncthreads();

        // issue next k-tile's loads; latency hides under the FMA loop below
        if (kk + KT < D_DIM) {
            a0l = *reinterpret_cast<const float4*>(xa + kk + KT);
            a0h = *reinterpret_cast<const float4*>(xa + kk + KT + 16);
            a1l = *reinterpret_cast<const float4*>(xb + kk + KT);
            a1h = *reinterpret_cast<const float4*>(xb + kk + KT + 16);
            b0l = *reinterpret_cast<const float4*>(wa + kk + KT);
            b0h = *reinterpret_cast<const float4*>(wa + kk + KT + 16);
            b1l = *reinterpret_cast<const float4*>(wb + kk + KT);
            b1h = *reinterpret_cast<const float4*>(wb + kk + KT + 16);
        }

#pragma unroll
        for (int k = 0; k < KT; ++k) {
            const float4 av0 = *reinterpret_cast<const float4*>(&As[k][rbase]);
            const float4 av1 = *reinterpret_cast<const float4*>(&As[k][rbase + 4]);
            const float4 bv0 = *reinterpret_cast<const float4*>(&Bs[k][c0]);
            const float4 bv1 = *reinterpret_cast<const float4*>(&Bs[k][c1]);
            const float am[8]  = {av0.x, av0.y, av0.z, av0.w, av1.x, av1.y, av1.z, av1.w};
            const float bn_[8] = {bv0.x, bv0.y, bv0.z, bv0.w, bv1.x, bv1.y, bv1.z, bv1.w};
#pragma unroll
            for (int i = 0; i < 8; ++i)
#pragma unroll
                for (int j = 0; j < 8; ++j) acc[i][j] += am[i] * bn_[j];
        }
    }

    const float4 bias0 = *reinterpret_cast<const float4*>(&bias[bn + c0]);
    const float4 bias1 = *reinterpret_cast<const float4*>(&bias[bn + c1]);
    const float bb[8] = {bias0.x, bias0.y, bias0.z, bias0.w, bias1.x, bias1.y, bias1.z, bias1.w};

#pragma unroll
    for (int i = 0; i < 8; ++i) {
        const size_t row = (size_t)(bm + rbase + i);
        float4 o0, o1;
        o0.x = acc[i][0] + bb[0]; o0.y = acc[i][1] + bb[1];
        o0.z = acc[i][2] + bb[2]; o0.w = acc[i][3] + bb[3];
        o1.x = acc[i][4] + bb[4]; o1.y = acc[i][5] + bb[5];
        o1.z = acc[i][6] + bb[6]; o1.w = acc[i][7] + bb[7];
        *reinterpret_cast<float4*>(&out[row * H_DIM + bn + c0]) = o0;
        *reinterpret_cast<float4*>(&out[row * H_DIM + bn + c1]) = o1;
    }
}

// ================= Scan (R11 exact: 64 blocks, 1 chain/lane, proven) =============
__device__ __forceinline__ void stage_chunk(const float* __restrict__ gio, float* dstbase,
                                            int c, int lane) {
    const float* src = gio + (size_t)(c * 32 + (lane >> 4)) * H_DIM + ((lane & 15) << 2);
#pragma unroll
    for (int i = 0; i < 8; ++i) {
        __builtin_amdgcn_global_load_lds(
            (const __attribute__((address_space(1))) void*)(src + (size_t)i * 4 * H_DIM),
            (__attribute__((address_space(3))) void*)(dstbase + i * 256),
            16, 0, 0);
    }
}

__device__ __forceinline__ void scan_wave(float* __restrict__ gio, float* sbuf,
                                          const int* flagrow, int lane,
                                          float* __restrict__ vout,
                                          float* __restrict__ thout, int chain) {
    float v = 0.f;
    float theta = 1.f;
    float tden = theta + EPS_F;
    float rs = __builtin_amdgcn_rcpf(tden);
    float es = fmaf(-tden, rs, 1.0f);
    float r1 = fmaf(es, rs, rs);
    float es2 = fmaf(-tden, r1, 1.0f);
    float r0 = fmaf(es2, r1, r1);
    float cl = 32.f * theta;
    const float kSixteen = 16.0f;

    if (flagrow) {
        while (__hip_atomic_load(&flagrow[0], __ATOMIC_ACQUIRE, __HIP_MEMORY_SCOPE_AGENT) < 4)
            __builtin_amdgcn_s_sleep(1);
    }
    stage_chunk(gio, sbuf, 0, lane);
    asm volatile("s_waitcnt vmcnt(0)" ::: "memory");

    for (int c = 0; c < NCHUNK; ++c) {
        if (c + 1 < NCHUNK) {
            if (((c + 1) & 3) == 0 && flagrow) {
                const int stn = (c + 1) >> 2;
                while (__hip_atomic_load(&flagrow[stn], __ATOMIC_ACQUIRE,
                                         __HIP_MEMORY_SCOPE_AGENT) < 4)
                    __builtin_amdgcn_s_sleep(1);
                asm volatile("s_waitcnt vmcnt(0)" ::: "memory");
                stage_chunk(gio, sbuf + ((c + 1) & 1) * 2048, c + 1, lane);
            } else {
                stage_chunk(gio, sbuf + ((c + 1) & 1) * 2048, c + 1, lane);
                // outstanding: stage(c)=8, stores(c-1)=32, stage(c+1)=8 -> retire oldest 8
                asm volatile("s_waitcnt vmcnt(40)" ::: "memory");
            }
        } else {
            asm volatile("s_waitcnt vmcnt(32)" ::: "memory");
        }
        __builtin_amdgcn_sched_barrier(0);

        const float* sb = sbuf + (c & 1) * 2048 + lane;
        float rr[32];
#pragma unroll
        for (int i = 0; i < 32; ++i) rr[i] = sb[i * 64];
        __builtin_amdgcn_sched_barrier(0);

        float* gout = gio + (size_t)c * 32 * H_DIM + lane;

#pragma unroll
        for (int u = 0; u < 32; ++u) {
            float vv = v * DECAY_F + rr[u];
            asm("v_med3_f32 %0, %0, -%1, %1" : "+v"(vv) : "v"(cl));
            v = vv;

            const float q0 = v * r0;
            const float e1 = fmaf(-tden, q0, v);
            const float nv = fmaf(e1, r0, q0);

            float spike = floorf(nv);
            asm("v_med3_f32 %0, %0, 0, %1" : "+v"(spike) : "v"(kSixteen));

            v = v - spike * theta;
            theta = theta + ALPHA_F * spike - ALPHA_F * (theta - 1.0f);

            tden = theta + EPS_F;
            const float rrcp = __builtin_amdgcn_rcpf(tden);
            const float ee = fmaf(-tden, rrcp, 1.0f);
            const float ra = fmaf(ee, rrcp, rrcp);
            const float ee2 = fmaf(-tden, ra, 1.0f);
            r0 = fmaf(ee2, ra, ra);
            cl = 32.f * theta;

            gout[(size_t)u * H_DIM] = spike;
        }
        __builtin_amdgcn_sched_barrier(0);
    }

    vout[chain]  = v;
    thout[chain] = theta;
}

// ================= fused kernel (R11 structure + KT=32 GEMM) =====================
// blocks 0..63: scan, ONE active wave each (threads 64..255 exit), 16KB dbuf,
//   s_setprio(1), 1 chain/lane (R11-proven).
// blocks 64..1087: GEMM 128x128 tiles, flat grid, s-tile-major (st = g>>5).
// LDS 33792B -> 4 blocks/CU (LDS) = 4 blocks/CU (VGPR at ~112-120) -> same
// co-residency as R11 but HALF the barrier count per tile.
// Sync: flags[bb*32+st] count to 4 (nt); __syncthreads drains stores, tid-0
// RELEASE fetch_add; scan ACQUIRE-polls ==4. Protocol proven R10-R12.
__global__ __launch_bounds__(256) void fused_kernel(const float* __restrict__ x,
                                                    const float* __restrict__ W,
                                                    const float* __restrict__ bias,
                                                    float* __restrict__ out,
                                                    float* __restrict__ vout,
                                                    float* __restrict__ thout,
                                                    int* __restrict__ flags) {
    __shared__ __align__(16) char smem_raw[2 * sizeof(float) * KT * 132];  // 33792B
    const int bid = blockIdx.x;

    if (bid >= NSCAN_BLOCKS) {
        float (*As)[132] = reinterpret_cast<float (*)[132]>(smem_raw);
        float (*Bs)[132] = reinterpret_cast<float (*)[132]>(smem_raw + sizeof(float) * KT * 132);

        const int g  = bid - NSCAN_BLOCKS;   // 0..1023
        const int st = g >> 5;               // s-tile 0..31 (outer)
        const int bb = (g >> 2) & 7;         // batch
        const int nt = g & 3;                // n-tile
        const int bm = bb * S_LEN + st * 128;
        const int bn = nt * 128;

        gemm_tile(x, W, bias, out, As, Bs, bm, bn);

        __syncthreads();   // all waves' stores retired before the release add
        if (threadIdx.x == 0) {
            __hip_atomic_fetch_add(&flags[bb * 32 + st], 1,
                                   __ATOMIC_RELEASE, __HIP_MEMORY_SCOPE_AGENT);
        }
        return;
    }

    // scan role: one active wave per block
    if (threadIdx.x >= 64) return;
    __builtin_amdgcn_s_setprio(1);

    const int lane = threadIdx.x;
    const int b  = bid >> 3;             // 0..7
    const int h0 = (bid & 7) << 6;       // 0,64,...,448

    float* sbuf = reinterpret_cast<float*>(smem_raw);
    float* gio = out + (size_t)b * S_LEN * H_DIM + h0;
    const int chain = b * H_DIM + h0 + lane;

    scan_wave(gio, sbuf, flags + b * 32, lane, vout, thout, chain);
}

// ================= fallback serial kernels (ws too small) ========================

__global__ __launch_bounds__(256) void gemm_kernel(const float* __restrict__ x,
                                                   const float* __restrict__ W,
                                                   const float* __restrict__ bias,
                                                   float* __restrict__ out) {
    __shared__ float As[KT][132];
    __shared__ float Bs[KT][132];
    const int bm = blockIdx.y * 128;
    const int bn = blockIdx.x * 128;
    gemm_tile(x, W, bias, out, As, Bs, bm, bn);
}

__global__ __launch_bounds__(64, 1) void scan_serial_kernel(float* __restrict__ io,
                                                            float* __restrict__ vout,
                                                            float* __restrict__ thout) {
    __shared__ __align__(16) float sbuf[4096];
    const int bid = blockIdx.x;
    const int lane = threadIdx.x;
    const int b  = bid >> 3;
    const int h0 = (bid & 7) << 6;
    float* gio = io + (size_t)b * S_LEN * H_DIM + h0;
    const int chain = b * H_DIM + h0 + lane;
    scan_wave(gio, sbuf, nullptr, lane, vout, thout, chain);
}

extern "C" void kernel_launch(void* const* d_in, const int* in_sizes, int n_in,
                              void* d_out, int out_size, void* d_ws, size_t ws_size,
                              hipStream_t stream) {
    const float* x    = (const float*)d_in[0];
    const float* W    = (const float*)d_in[1];
    const float* bias = (const float*)d_in[2];

    float* out   = (float*)d_out;
    float* vout  = out + (size_t)B_DIM * S_LEN * H_DIM;
    float* thout = vout + B_DIM * H_DIM;

    if (ws_size >= 1024) {
        int* flags = (int*)d_ws;
        hipMemsetAsync(flags, 0, 1024, stream);
        fused_kernel<<<NSCAN_BLOCKS + 1024, 256, 0, stream>>>(x, W, bias, out,
                                                              vout, thout, flags);
    } else {
        dim3 grid(H_DIM / 128, (B_DIM * S_LEN) / 128);
        gemm_kernel<<<grid, 256, 0, stream>>>(x, W, bias, out);
        scan_serial_kernel<<<NSCAN_BLOCKS, 64, 0, stream>>>(out, vout, thout);
    }
}